// Round 3
// baseline (3827.175 us; speedup 1.0000x reference)
//
#include <hip/hip_runtime.h>
#include <hip/hip_bf16.h>
#include <type_traits>

#define B_  8
#define LV_ 1024
#define LL_ 1024
#define LO_ 512
#define E_  768
#define H_  12
#define D_  64
#define S_  2048  // LV+LL

// ---------- helpers ----------
__device__ inline void ld_bf16x8(const __hip_bfloat16* p, float* o) {
  uint4 r = *reinterpret_cast<const uint4*>(p);
  unsigned int u[4] = {r.x, r.y, r.z, r.w};
#pragma unroll
  for (int i = 0; i < 4; ++i) {
    o[2*i]   = __uint_as_float(u[i] << 16);
    o[2*i+1] = __uint_as_float(u[i] & 0xFFFF0000u);
  }
}

template <typename T>
__device__ inline void ld8(const T* p, float* o);

template <>
__device__ inline void ld8<__hip_bfloat16>(const __hip_bfloat16* p, float* o) {
  ld_bf16x8(p, o);
}

template <>
__device__ inline void ld8<float>(const float* p, float* o) {
  const float4* q = reinterpret_cast<const float4*>(p);
  float4 a = q[0], b = q[1];
  o[0] = a.x; o[1] = a.y; o[2] = a.z; o[3] = a.w;
  o[4] = b.x; o[5] = b.y; o[6] = b.z; o[7] = b.w;
}

// ---------- GEMM: C[r][c] = sum_k A[r][k]*W[c][k] + bias[c] ----------
// A: R x 768 (TA) row-major, W: N x 768 fp32 row-major, C: R x N (TC).
// 64x64 tile, BK=32, 256 threads, 4x4 outputs/thread, fp32 accum.
template <typename TA, typename TC>
__global__ __launch_bounds__(256) void gemm_bt(
    const TA* __restrict__ A,
    const float* __restrict__ W,
    const float* __restrict__ bias,
    TC* __restrict__ C,
    int R, int N)
{
  constexpr int K = E_;
  __shared__ float As[64][33];
  __shared__ float Ws[64][33];
  const int tid  = threadIdx.x;
  const int row0 = blockIdx.x * 64;
  const int col0 = blockIdx.y * 64;
  const int tx = tid & 15;   // col group
  const int ty = tid >> 4;   // row group
  const int lrow = tid >> 2;
  const int lk   = (tid & 3) * 8;
  float acc[4][4] = {};

  for (int k0 = 0; k0 < K; k0 += 32) {
    float ta[8], tw[8];
    ld8<TA>(A + (size_t)(row0 + lrow) * K + k0 + lk, ta);
    ld8<float>(W + (size_t)(col0 + lrow) * K + k0 + lk, tw);
    __syncthreads();  // previous compute done before overwrite
#pragma unroll
    for (int i = 0; i < 8; ++i) { As[lrow][lk + i] = ta[i]; Ws[lrow][lk + i] = tw[i]; }
    __syncthreads();
#pragma unroll
    for (int kk = 0; kk < 32; ++kk) {
      float a[4], w[4];
#pragma unroll
      for (int i = 0; i < 4; ++i) { a[i] = As[ty*4 + i][kk]; w[i] = Ws[tx*4 + i][kk]; }
#pragma unroll
      for (int i = 0; i < 4; ++i)
#pragma unroll
        for (int j = 0; j < 4; ++j) acc[i][j] += a[i] * w[j];
    }
  }

#pragma unroll
  for (int i = 0; i < 4; ++i) {
    const int r = row0 + ty*4 + i;
#pragma unroll
    for (int j = 0; j < 4; ++j) {
      const int c = col0 + tx*4 + j;
      float v = acc[i][j] + bias[c];
      if constexpr (std::is_same_v<TC, float>) C[(size_t)r * N + c] = v;
      else                                     C[(size_t)r * N + c] = __float2bfloat16(v);
    }
  }
}

// ---------- fused attention + head-average ----------
// grid: B*(LO/4) = 1024 blocks, 256 threads = 4 waves; wave w owns row qt*4+w.
// Loops over all 12 heads internally; accumulates head-sum of probabilities
// in registers (pavg[32]) and writes attn_avg directly -> no global p buffer.
__global__ __launch_bounds__(256) void attn_fused(
    const __hip_bfloat16* __restrict__ q1ws,
    const __hip_bfloat16* __restrict__ q2ws,
    const __hip_bfloat16* __restrict__ k1ws,
    const __hip_bfloat16* __restrict__ v1ws,
    const __hip_bfloat16* __restrict__ k2ws,
    const __hip_bfloat16* __restrict__ v2ws,
    const float* __restrict__ mask,
    float* __restrict__ avg_out,           // [B][LO][S] fp32
    __hip_bfloat16* __restrict__ ctx)      // [B][LO][E] bf16 (ws)
{
  __shared__ float kv[64][65];     // K/V chunk, padded (2-way bank aliasing = free)
  __shared__ float qls[4][2][64];  // per-wave q1,q2 rows (current head)
  __shared__ float pls[4][2048];   // per-wave normalized probabilities (current head)

  const int tid  = threadIdx.x;
  const int w    = tid >> 6;
  const int lane = tid & 63;
  const int qt   = blockIdx.x & 127;   // LO/4 = 128
  const int b    = blockIdx.x >> 7;
  const int row  = qt * 4 + w;

  const int ck = tid >> 2;         // key-in-chunk 0..63
  const int cd = (tid & 3) * 16;   // d offset (16 elems = 2x8)

  float pavg[32] = {};

#pragma unroll 1
  for (int h = 0; h < H_; ++h) {
    // per-wave q rows for this head (in-wave write->read, no barrier needed)
    qls[w][0][lane] = __bfloat162float(q1ws[((size_t)(b*LO_ + row))*E_ + h*64 + lane]);
    qls[w][1][lane] = __bfloat162float(q2ws[((size_t)(b*LO_ + row))*E_ + h*64 + lane]);

    float s_reg[32];

    // Phase A: scores. chunks 0..15 = source1 (q1,k1), 16..31 = source2 (q2,k2)
#pragma unroll 1
    for (int c = 0; c < 32; ++c) {
      const __hip_bfloat16* base = (c < 16) ? k1ws : k2ws;
      const int sidx = (c & 15) * 64 + ck;
      const __hip_bfloat16* src = base + ((size_t)(b*1024 + sidx))*E_ + h*64 + cd;
      float t8a[8], t8b[8];
      ld_bf16x8(src, t8a);
      ld_bf16x8(src + 8, t8b);
      __syncthreads();  // previous chunk's compute done before overwrite
#pragma unroll
      for (int i = 0; i < 8; ++i) { kv[ck][cd + i] = t8a[i]; kv[ck][cd + 8 + i] = t8b[i]; }
      __syncthreads();
      const float* qv = qls[w][c >> 4];
      float s = 0.f;
#pragma unroll
      for (int d2 = 0; d2 < 64; ++d2) s += qv[d2] * kv[lane][d2];
      s_reg[c] = s * 0.125f + mask[(size_t)row * S_ + c*64 + lane];
    }

    // softmax over 2048 (32 regs x 64 lanes), per wave
    float m = -3.0e38f;
#pragma unroll
    for (int c = 0; c < 32; ++c) m = fmaxf(m, s_reg[c]);
#pragma unroll
    for (int off = 32; off >= 1; off >>= 1) m = fmaxf(m, __shfl_xor(m, off, 64));
    float sum = 0.f;
#pragma unroll
    for (int c = 0; c < 32; ++c) { s_reg[c] = __expf(s_reg[c] - m); sum += s_reg[c]; }
#pragma unroll
    for (int off = 32; off >= 1; off >>= 1) sum += __shfl_xor(sum, off, 64);
    const float inv = 1.0f / sum;

#pragma unroll
    for (int c = 0; c < 32; ++c) {
      const float pv = s_reg[c] * inv;
      pavg[c] += pv;
      pls[w][c*64 + lane] = pv;   // in-wave write->read
    }

    // Phase B: ctx[d=lane] = sum_j p[j] * V[j][d]
    float acc = 0.f;
#pragma unroll 1
    for (int c = 0; c < 32; ++c) {
      const __hip_bfloat16* base = (c < 16) ? v1ws : v2ws;
      const int sidx = (c & 15) * 64 + ck;
      const __hip_bfloat16* src = base + ((size_t)(b*1024 + sidx))*E_ + h*64 + cd;
      float t8a[8], t8b[8];
      ld_bf16x8(src, t8a);
      ld_bf16x8(src + 8, t8b);
      __syncthreads();
#pragma unroll
      for (int i = 0; i < 8; ++i) { kv[ck][cd + i] = t8a[i]; kv[ck][cd + 8 + i] = t8b[i]; }
      __syncthreads();
      const float* pp = &pls[w][c*64];
      float a = 0.f;
#pragma unroll
      for (int kk = 0; kk < 64; ++kk) a += pp[kk] * kv[kk][lane];
      acc += a;
    }
    ctx[((size_t)(b*LO_ + row))*E_ + h*64 + lane] = __float2bfloat16(acc);
  }

  // write head-averaged attention (fp32 output)
  constexpr float invH = 1.0f / 12.0f;
#pragma unroll
  for (int c = 0; c < 32; ++c)
    avg_out[((size_t)(b*LO_ + row))*S_ + c*64 + lane] = pavg[c] * invH;
}

// ---------- launch ----------
extern "C" void kernel_launch(void* const* d_in, const int* in_sizes, int n_in,
                              void* d_out, int out_size, void* d_ws, size_t ws_size,
                              hipStream_t stream) {
  const float* V    = (const float*)d_in[0];
  const float* Lm   = (const float*)d_in[1];
  const float* O    = (const float*)d_in[2];
  const float* mask = (const float*)d_in[3];
  const float* w1   = (const float*)d_in[4];
  const float* b1   = (const float*)d_in[5];
  const float* w2   = (const float*)d_in[6];
  const float* b2   = (const float*)d_in[7];
  const float* ow   = (const float*)d_in[8];
  const float* ob   = (const float*)d_in[9];
  float* out = (float*)d_out;

  // ws layout (bf16 elems): q1,q2: B*LO*E each; k1,v1,k2,v2: B*1024*E each; ctx: B*LO*E
  // total = 34,603,008 bf16 = 69.2 MB
  __hip_bfloat16* ws  = (__hip_bfloat16*)d_ws;
  __hip_bfloat16* q1  = ws;
  __hip_bfloat16* q2  = q1 + (size_t)B_*LO_*E_;
  __hip_bfloat16* k1  = q2 + (size_t)B_*LO_*E_;
  __hip_bfloat16* v1  = k1 + (size_t)B_*LV_*E_;
  __hip_bfloat16* k2  = v1 + (size_t)B_*LV_*E_;
  __hip_bfloat16* v2  = k2 + (size_t)B_*LL_*E_;
  __hip_bfloat16* ctx = v2 + (size_t)B_*LL_*E_;

  dim3 blk(256);
  // projections: split(in_w, 3): wq = rows[0:768), wk = [768:1536), wv = [1536:2304)
  gemm_bt<float, __hip_bfloat16><<<dim3(4096/64, 12), blk, 0, stream>>>(O,  w1,             b1,        q1, 4096, 768);
  gemm_bt<float, __hip_bfloat16><<<dim3(4096/64, 12), blk, 0, stream>>>(O,  w2,             b2,        q2, 4096, 768);
  gemm_bt<float, __hip_bfloat16><<<dim3(8192/64, 12), blk, 0, stream>>>(V,  w1 + 768*768,   b1 + 768,  k1, 8192, 768);
  gemm_bt<float, __hip_bfloat16><<<dim3(8192/64, 12), blk, 0, stream>>>(V,  w1 + 2*768*768, b1 + 1536, v1, 8192, 768);
  gemm_bt<float, __hip_bfloat16><<<dim3(8192/64, 12), blk, 0, stream>>>(Lm, w2 + 768*768,   b2 + 768,  k2, 8192, 768);
  gemm_bt<float, __hip_bfloat16><<<dim3(8192/64, 12), blk, 0, stream>>>(Lm, w2 + 2*768*768, b2 + 1536, v2, 8192, 768);

  // fused attention: writes ctx (ws, bf16) and attn_avg (d_out tail, fp32) directly
  attn_fused<<<dim3(B_*(LO_/4)), blk, 0, stream>>>(q1, q2, k1, v1, k2, v2, mask,
                                                   out + (size_t)B_*LO_*E_, ctx);

  // output projection: bf16 ctx -> fp32 out
  gemm_bt<__hip_bfloat16, float><<<dim3(4096/64, 12), blk, 0, stream>>>(ctx, ow, ob, out, 4096, 768);
}

// Round 4
// 1063.681 us; speedup vs baseline: 3.5980x; 3.5980x over previous
//
#include <hip/hip_runtime.h>
#include <hip/hip_bf16.h>
#include <type_traits>

#define B_  8
#define LO_ 512
#define E_  768
#define H_  12
#define S_  2048

typedef __attribute__((ext_vector_type(8))) short bf16x8;
typedef __attribute__((ext_vector_type(4))) float f32x4;
#define MFMA16(a,b,c) __builtin_amdgcn_mfma_f32_16x16x32_bf16(a, b, c, 0, 0, 0)

__device__ inline short f2bf(float f) {
  __hip_bfloat16 h = __float2bfloat16(f);
  return *reinterpret_cast<short*>(&h);
}
__device__ inline float bf2f(short s) {
  unsigned int u = ((unsigned int)(unsigned short)s) << 16;
  return __uint_as_float(u);
}

// ================= MFMA GEMM: C[r][c] = sum_k A[r][k]*W[c][k] + bias[c] ==========
// A: R x 768 fp32, W: 768 x 768 fp32 (row-major, row=out col), C: R x 768 (TC).
// 64x64 tile, BK=64, 256 thr = 4 waves; wave w: rows w*16..+15, all 64 cols.
template <typename TC>
__global__ __launch_bounds__(256) void gemm_mfma(
    const float* __restrict__ A, const float* __restrict__ W,
    const float* __restrict__ bias, TC* __restrict__ C, int R)
{
  constexpr int N = 768, K = 768;
  __shared__ short As[64*72] __attribute__((aligned(16)));
  __shared__ short Ws[64*72] __attribute__((aligned(16)));
  const int tid = threadIdx.x, wv = tid >> 6, lane = tid & 63;
  const int quad = lane >> 4, l15 = lane & 15;
  const int r0 = blockIdx.x * 64, c0 = blockIdx.y * 64;
  const int srow = tid >> 2, sk = (tid & 3) * 16;

  f32x4 acc[4] = {};

  for (int k0 = 0; k0 < K; k0 += 64) {
    float a16[16], w16[16];
    const float4* ga = (const float4*)(A + (size_t)(r0 + srow) * K + k0 + sk);
    const float4* gw = (const float4*)(W + (size_t)(c0 + srow) * K + k0 + sk);
#pragma unroll
    for (int i = 0; i < 4; ++i) {
      float4 va = ga[i]; a16[4*i] = va.x; a16[4*i+1] = va.y; a16[4*i+2] = va.z; a16[4*i+3] = va.w;
      float4 vw = gw[i]; w16[4*i] = vw.x; w16[4*i+1] = vw.y; w16[4*i+2] = vw.z; w16[4*i+3] = vw.w;
    }
    bf16x8 pa[2], pw[2];
#pragma unroll
    for (int g = 0; g < 2; ++g)
#pragma unroll
      for (int i = 0; i < 8; ++i) { pa[g][i] = f2bf(a16[g*8+i]); pw[g][i] = f2bf(w16[g*8+i]); }
    __syncthreads();   // previous iteration's frag reads complete
    *(bf16x8*)&As[srow*72 + sk]     = pa[0];
    *(bf16x8*)&As[srow*72 + sk + 8] = pa[1];
    *(bf16x8*)&Ws[srow*72 + sk]     = pw[0];
    *(bf16x8*)&Ws[srow*72 + sk + 8] = pw[1];
    __syncthreads();

    bf16x8 af0 = *(const bf16x8*)&As[(wv*16 + l15)*72 +      quad*8];
    bf16x8 af1 = *(const bf16x8*)&As[(wv*16 + l15)*72 + 32 + quad*8];
#pragma unroll
    for (int ct = 0; ct < 4; ++ct) {
      bf16x8 bf0 = *(const bf16x8*)&Ws[(ct*16 + l15)*72 +      quad*8];
      bf16x8 bf1 = *(const bf16x8*)&Ws[(ct*16 + l15)*72 + 32 + quad*8];
      acc[ct] = MFMA16(af0, bf0, acc[ct]);
      acc[ct] = MFMA16(af1, bf1, acc[ct]);
    }
  }

#pragma unroll
  for (int ct = 0; ct < 4; ++ct) {
    const int col = c0 + ct*16 + l15;
    const float bv = bias[col];
#pragma unroll
    for (int r = 0; r < 4; ++r) {
      const int row = r0 + wv*16 + quad*4 + r;       // C layout: row=quad*4+reg, col=lane&15
      const float v = acc[ct][r] + bv;
      if constexpr (std::is_same_v<TC, float>) C[(size_t)row * N + col] = v;
      else                                     C[(size_t)row * N + col] = __float2bfloat16(v);
    }
  }
}

// ================= stats kernel: per-row softmax (m, 1/l) over full 2048 =========
// grid: (b,h,qt16) = 8*12*32 = 3072 blocks, 256 thr = 4 waves.
__global__ __launch_bounds__(256) void attn_stats(
    const __hip_bfloat16* __restrict__ q1, const __hip_bfloat16* __restrict__ q2,
    const __hip_bfloat16* __restrict__ k1, const __hip_bfloat16* __restrict__ k2,
    const float* __restrict__ mask, float* __restrict__ stats)
{
  __shared__ short kb[256*72]  __attribute__((aligned(16)));
  __shared__ short qt_[2*16*72] __attribute__((aligned(16)));
  __shared__ float smm[4][16], sml[4][16];

  const int tid = threadIdx.x, wv = tid >> 6, lane = tid & 63;
  const int quad = lane >> 4, l15 = lane & 15;
  const int qt = blockIdx.x & 31, h = (blockIdx.x >> 5) % 12, b = blockIdx.x / 384;
  const int r0 = qt * 16;

  if (tid < 128) {  // stage q1,q2 tiles: src=tid>>6, row=(tid>>2)&15, c=(tid&3)*16
    const int src = tid >> 6, row = (tid >> 2) & 15, c = (tid & 3) * 16;
    const uint4* g = (const uint4*)((src ? q2 : q1) + ((size_t)(b*LO_ + r0 + row))*E_ + h*64 + c);
    *(uint4*)&qt_[src*1152 + row*72 + c]     = g[0];
    *(uint4*)&qt_[src*1152 + row*72 + c + 8] = g[1];
  }
  __syncthreads();
  bf16x8 qa[2][2];
#pragma unroll
  for (int s = 0; s < 2; ++s)
#pragma unroll
    for (int ks = 0; ks < 2; ++ks)
      qa[s][ks] = *(const bf16x8*)&qt_[s*1152 + l15*72 + ks*32 + quad*8];

  float m_l[4] = {-3.0e38f, -3.0e38f, -3.0e38f, -3.0e38f};
  float l_l[4] = {};

#pragma unroll 1
  for (int it = 0; it < 8; ++it) {
    const __hip_bfloat16* ksrc = (it < 4) ? k1 : k2;
    const int kb0 = (it & 3) * 256;
    const uint4* g = (const uint4*)(ksrc + ((size_t)(b*1024 + kb0 + tid))*E_ + h*64);
    uint4 tmp[8];
#pragma unroll
    for (int i = 0; i < 8; ++i) tmp[i] = g[i];
    __syncthreads();
#pragma unroll
    for (int i = 0; i < 8; ++i) *(uint4*)&kb[tid*72 + i*8] = tmp[i];
    __syncthreads();
    const int s = it >> 2;
#pragma unroll
    for (int ct = 0; ct < 4; ++ct) {
      const int nb = wv*64 + ct*16;
      bf16x8 b0 = *(const bf16x8*)&kb[(nb + l15)*72 +      quad*8];
      bf16x8 b1 = *(const bf16x8*)&kb[(nb + l15)*72 + 32 + quad*8];
      f32x4 sacc = {};
      sacc = MFMA16(qa[s][0], b0, sacc);
      sacc = MFMA16(qa[s][1], b1, sacc);
      const int colg = it*256 + nb + l15;
#pragma unroll
      for (int r = 0; r < 4; ++r) {
        const float v = sacc[r]*0.125f + mask[(size_t)(r0 + quad*4 + r)*S_ + colg];
        const float mn = fmaxf(m_l[r], v);
        l_l[r] = l_l[r]*__expf(m_l[r]-mn) + __expf(v-mn);
        m_l[r] = mn;
      }
    }
  }
  // merge across 16 lanes of each quad
#pragma unroll
  for (int off = 1; off < 16; off <<= 1) {
#pragma unroll
    for (int r = 0; r < 4; ++r) {
      const float mo = __shfl_xor(m_l[r], off, 64);
      const float lo = __shfl_xor(l_l[r], off, 64);
      const float mn = fmaxf(m_l[r], mo);
      l_l[r] = l_l[r]*__expf(m_l[r]-mn) + lo*__expf(mo-mn);
      m_l[r] = mn;
    }
  }
  if (l15 == 0) {
#pragma unroll
    for (int r = 0; r < 4; ++r) { smm[wv][quad*4+r] = m_l[r]; sml[wv][quad*4+r] = l_l[r]; }
  }
  __syncthreads();
  if (tid < 16) {
    float m = smm[0][tid], l = sml[0][tid];
#pragma unroll
    for (int ww = 1; ww < 4; ++ww) {
      const float mo = smm[ww][tid], lo = sml[ww][tid];
      const float mn = fmaxf(m, mo);
      l = l*__expf(m-mn) + lo*__expf(mo-mn);
      m = mn;
    }
    const size_t idx = (((size_t)(b*H_ + h))*LO_ + r0 + tid) * 2;
    stats[idx] = m; stats[idx+1] = 1.0f / l;
  }
}

// ================= main attention: P (exact), pavg in LDS, PV by MFMA ============
// grid: (b, qt16, src) = 8*32*2 = 512 blocks, 512 thr = 8 waves, dynamic LDS 149248 B.
#define OFF_PAVG 0
#define OFF_MASK 65536
#define OFF_KBUF 98560
#define OFF_VT   116992
#define OFF_QT   134400
#define OFF_PST  136704
#define OFF_OBUF 141056
#define SMEM_MAIN 149248

__global__ __launch_bounds__(512, 1) void attn_main(
    const __hip_bfloat16* __restrict__ q1, const __hip_bfloat16* __restrict__ q2,
    const __hip_bfloat16* __restrict__ k1, const __hip_bfloat16* __restrict__ v1,
    const __hip_bfloat16* __restrict__ k2, const __hip_bfloat16* __restrict__ v2,
    const float* __restrict__ mask, const float* __restrict__ stats,
    float* __restrict__ ctx, float* __restrict__ avg)
{
  extern __shared__ char smem[];
  float* pavg = (float*)(smem + OFF_PAVG);   // [16][1024]
  short* mls  = (short*)(smem + OFF_MASK);   // [16][1032] bf16
  short* kbuf = (short*)(smem + OFF_KBUF);   // [128][72] bf16
  short* vT   = (short*)(smem + OFF_VT);     // [64][136] bf16 (transposed V)
  short* qtl  = (short*)(smem + OFF_QT);     // [16][72] bf16
  short* pst  = (short*)(smem + OFF_PST);    // [16][136] bf16
  float* obuf = (float*)(smem + OFF_OBUF);   // [8][256]

  const int tid = threadIdx.x, wv = tid >> 6, lane = tid & 63;
  const int quad = lane >> 4, l15 = lane & 15;
  const int src = blockIdx.x & 1, qt = (blockIdx.x >> 1) & 31, b = blockIdx.x >> 6;
  const int r0 = qt * 16;
  const __hip_bfloat16* qws = src ? q2 : q1;
  const __hip_bfloat16* kws = src ? k2 : k1;
  const __hip_bfloat16* vws = src ? v2 : v1;

  // zero pavg
#pragma unroll
  for (int i = 0; i < 8; ++i) ((float4*)pavg)[tid + i*512] = float4{0.f,0.f,0.f,0.f};

  // stage mask tile (16 x 1024, bf16) once per block
  {
    const int row = tid >> 5, c00 = (tid & 31) * 32;
    const float4* g = (const float4*)(mask + (size_t)(r0 + row)*S_ + src*1024 + c00);
    short tmp[32];
#pragma unroll
    for (int i = 0; i < 8; ++i) {
      float4 v = g[i];
      tmp[4*i] = f2bf(v.x); tmp[4*i+1] = f2bf(v.y); tmp[4*i+2] = f2bf(v.z); tmp[4*i+3] = f2bf(v.w);
    }
#pragma unroll
    for (int i = 0; i < 4; ++i) *(bf16x8*)&mls[row*1032 + c00 + i*8] = *(bf16x8*)&tmp[i*8];
  }

  const int cpr = wv >> 2;   // which 64-key half of the staged 128-pair
  const int ct  = wv & 3;    // 16-wide col/dim tile

#pragma unroll 1
  for (int h = 0; h < H_; ++h) {
    __syncthreads();  // protect qtl/kbuf/vT/pst/obuf reuse from previous head
    if (tid < 64) {
      const int row = tid >> 2, c = (tid & 3) * 16;
      const uint4* g = (const uint4*)(qws + ((size_t)(b*LO_ + r0 + row))*E_ + h*64 + c);
      *(uint4*)&qtl[row*72 + c]     = g[0];
      *(uint4*)&qtl[row*72 + c + 8] = g[1];
    }
    __syncthreads();
    bf16x8 qa0 = *(const bf16x8*)&qtl[l15*72 +      quad*8];
    bf16x8 qa1 = *(const bf16x8*)&qtl[l15*72 + 32 + quad*8];

    float m_r[4], il_r[4];
#pragma unroll
    for (int r = 0; r < 4; ++r) {
      const size_t idx = (((size_t)(b*H_ + h))*LO_ + r0 + quad*4 + r) * 2;
      m_r[r] = stats[idx]; il_r[r] = stats[idx+1];
    }

    f32x4 oacc = {};

#pragma unroll 1
    for (int cp = 0; cp < 8; ++cp) {
      // ---- stage K pair + transposed V pair ----
      const int row = tid >> 2, c16 = (tid & 3) * 16;
      const uint4* gk = (const uint4*)(kws + ((size_t)(b*1024 + cp*128 + row))*E_ + h*64 + c16);
      uint4 k0 = gk[0], k1v = gk[1];
      const unsigned short* gv = (const unsigned short*)(vws + ((size_t)(b*1024 + cp*128 + row))*E_ + h*64 + c16);
      unsigned short vv[16];
#pragma unroll
      for (int i = 0; i < 16; ++i) vv[i] = gv[i];
      __syncthreads();   // previous cp's LDS reads complete
      *(uint4*)&kbuf[row*72 + c16]     = k0;
      *(uint4*)&kbuf[row*72 + c16 + 8] = k1v;
#pragma unroll
      for (int i = 0; i < 16; ++i) ((unsigned short*)vT)[(c16 + i)*136 + row] = vv[i];
      __syncthreads();

      // ---- recompute S subtile (16 x 16) ----
      const int nb = cpr*64 + ct*16;
      bf16x8 kb0 = *(const bf16x8*)&kbuf[(nb + l15)*72 +      quad*8];
      bf16x8 kb1 = *(const bf16x8*)&kbuf[(nb + l15)*72 + 32 + quad*8];
      f32x4 sacc = {};
      sacc = MFMA16(qa0, kb0, sacc);
      sacc = MFMA16(qa1, kb1, sacc);

      // ---- exact P, scatter to pstage (bf16) ----
#pragma unroll
      for (int r = 0; r < 4; ++r) {
        const int lrow = quad*4 + r;
        const float mv = bf2f(mls[lrow*1032 + cp*128 + nb + l15]);
        const float p = __expf(sacc[r]*0.125f + mv - m_r[r]) * il_r[r];
        pst[lrow*136 + nb + l15] = f2bf(p);
      }
      __syncthreads();

      // ---- pavg += P (RMW from pstage, clean b128 pattern) ----
      {
        const int prow = tid >> 5, pc = (tid & 31) * 4;
        float4* pa = (float4*)&pavg[prow*1024 + cp*128 + pc];
        float4 cur = *pa;
        const short* ps = &pst[prow*136 + pc];
        cur.x += bf2f(ps[0]); cur.y += bf2f(ps[1]); cur.z += bf2f(ps[2]); cur.w += bf2f(ps[3]);
        *pa = cur;
      }

      // ---- PV: oacc += P[16][64(cpr)] * V[64][16(ct)] ----
      bf16x8 pa0 = *(const bf16x8*)&pst[l15*136 + cpr*64 +      quad*8];
      bf16x8 pa1 = *(const bf16x8*)&pst[l15*136 + cpr*64 + 32 + quad*8];
      bf16x8 vb0 = *(const bf16x8*)&vT[(ct*16 + l15)*136 + cpr*64 +      quad*8];
      bf16x8 vb1 = *(const bf16x8*)&vT[(ct*16 + l15)*136 + cpr*64 + 32 + quad*8];
      oacc = MFMA16(pa0, vb0, oacc);
      oacc = MFMA16(pa1, vb1, oacc);
    }

    // ---- merge wave pairs (wv, wv+4) and accumulate ctx ----
#pragma unroll
    for (int r = 0; r < 4; ++r) obuf[wv*256 + r*64 + lane] = oacc[r];
    __syncthreads();
#pragma unroll
    for (int e0 = 0; e0 < 2; ++e0) {
      const int e = tid + e0*512;
      const int row = e >> 6, dim = e & 63;
      const int idx = (row & 3)*64 + (row >> 2)*16 + (dim & 15);
      const float v = obuf[(dim >> 4)*256 + idx] + obuf[((dim >> 4) + 4)*256 + idx];
      atomicAdd(&ctx[((size_t)(b*LO_ + r0 + row))*E_ + h*64 + dim], v);
    }
  }

  // ---- write head-averaged attention (fp32) ----
  {
    constexpr float invH = 1.0f / 12.0f;
    const int row = tid >> 5, c00 = (tid & 31) * 32;
    float4* dst = (float4*)(avg + (size_t)(b*LO_ + r0 + row)*S_ + src*1024 + c00);
    const float4* sp = (const float4*)&pavg[row*1024 + c00];
#pragma unroll
    for (int i = 0; i < 8; ++i) {
      float4 v = sp[i];
      v.x *= invH; v.y *= invH; v.z *= invH; v.w *= invH;
      dst[i] = v;
    }
  }
}

// ================= launch =================
extern "C" void kernel_launch(void* const* d_in, const int* in_sizes, int n_in,
                              void* d_out, int out_size, void* d_ws, size_t ws_size,
                              hipStream_t stream) {
  const float* V    = (const float*)d_in[0];
  const float* Lm   = (const float*)d_in[1];
  const float* O    = (const float*)d_in[2];
  const float* mask = (const float*)d_in[3];
  const float* w1   = (const float*)d_in[4];
  const float* b1   = (const float*)d_in[5];
  const float* w2   = (const float*)d_in[6];
  const float* b2   = (const float*)d_in[7];
  const float* ow   = (const float*)d_in[8];
  const float* ob   = (const float*)d_in[9];
  float* out = (float*)d_out;

  // ws: bf16 q1,q2 (4096x768 each), k1,v1,k2,v2 (8192x768 each); then fp32 ctx, stats
  __hip_bfloat16* ws  = (__hip_bfloat16*)d_ws;
  __hip_bfloat16* q1  = ws;
  __hip_bfloat16* q2  = q1 + (size_t)4096*768;
  __hip_bfloat16* k1  = q2 + (size_t)4096*768;
  __hip_bfloat16* v1  = k1 + (size_t)8192*768;
  __hip_bfloat16* k2  = v1 + (size_t)8192*768;
  __hip_bfloat16* v2  = k2 + (size_t)8192*768;
  float* ctx   = (float*)(v2 + (size_t)8192*768);
  float* stats = ctx + (size_t)4096*768;

  hipMemsetAsync(ctx, 0, (size_t)4096*768*4, stream);

  dim3 blk(256);
  gemm_mfma<__hip_bfloat16><<<dim3(64, 12),  blk, 0, stream>>>(O,  w1,             b1,        q1, 4096);
  gemm_mfma<__hip_bfloat16><<<dim3(64, 12),  blk, 0, stream>>>(O,  w2,             b2,        q2, 4096);
  gemm_mfma<__hip_bfloat16><<<dim3(128, 12), blk, 0, stream>>>(V,  w1 + 768*768,   b1 + 768,  k1, 8192);
  gemm_mfma<__hip_bfloat16><<<dim3(128, 12), blk, 0, stream>>>(V,  w1 + 2*768*768, b1 + 1536, v1, 8192);
  gemm_mfma<__hip_bfloat16><<<dim3(128, 12), blk, 0, stream>>>(Lm, w2 + 768*768,   b2 + 768,  k2, 8192);
  gemm_mfma<__hip_bfloat16><<<dim3(128, 12), blk, 0, stream>>>(Lm, w2 + 2*768*768, b2 + 1536, v2, 8192);

  attn_stats<<<dim3(3072), blk, 0, stream>>>(q1, q2, k1, k2, mask, stats);

  hipFuncSetAttribute((const void*)attn_main, hipFuncAttributeMaxDynamicSharedMemorySize, SMEM_MAIN);
  attn_main<<<dim3(512), dim3(512), SMEM_MAIN, stream>>>(q1, q2, k1, v1, k2, v2, mask, stats,
                                                         ctx, out + (size_t)4096*768);

  gemm_mfma<float><<<dim3(64, 12), blk, 0, stream>>>(ctx, ow, ob, out, 4096);
}